// Round 1
// baseline (200.562 us; speedup 1.0000x reference)
//
#include <hip/hip_runtime.h>

// IoU mean over B=1e6 x NBOX=6 midpoint-format box pairs with sentinel-masked
// truth rows. Streaming reduction: 192 MB in, 1 float out -> HBM-bound,
// roofline ~30.5 us at 6.3 TB/s achievable.

#define BLOCKS 1024
#define THREADS 256

__global__ __launch_bounds__(THREADS) void iou_partial(
    const float4* __restrict__ pred,
    const float4* __restrict__ truth,
    float* __restrict__ partials,   // [BLOCKS][2]: {sum_iou, sum_valid}
    int n)                          // number of (b,box) pairs
{
    int tid = blockIdx.x * blockDim.x + threadIdx.x;
    int stride = gridDim.x * blockDim.x;

    float s_iou = 0.0f;
    float s_cnt = 0.0f;

    for (int i = tid; i < n; i += stride) {
        float4 p = pred[i];
        float4 t = truth[i];
        // valid iff truth row is not the sentinel [-1,-1,-1,-1]
        bool valid = !(t.x == -1.0f && t.y == -1.0f &&
                       t.z == -1.0f && t.w == -1.0f);
        if (valid) {
            float p_x1 = p.x - p.z * 0.5f;
            float p_y1 = p.y - p.w * 0.5f;
            float p_x2 = p.x + p.z * 0.5f;
            float p_y2 = p.y + p.w * 0.5f;
            float t_x1 = t.x - t.z * 0.5f;
            float t_y1 = t.y - t.w * 0.5f;
            float t_x2 = t.x + t.z * 0.5f;
            float t_y2 = t.y + t.w * 0.5f;

            float x1 = fmaxf(p_x1, t_x1);
            float y1 = fmaxf(p_y1, t_y1);
            float x2 = fminf(p_x2, t_x2);
            float y2 = fminf(p_y2, t_y2);

            float inter  = fmaxf(x2 - x1, 0.0f) * fmaxf(y2 - y1, 0.0f);
            float area_p = fabsf((p_x2 - p_x1) * (p_y2 - p_y1));
            float area_t = fabsf((t_x2 - t_x1) * (t_y2 - t_y1));

            s_iou += inter / (area_p + area_t - inter + 1e-6f);
            s_cnt += 1.0f;
        }
    }

    // wave (64-lane) shuffle reduction
    for (int off = 32; off > 0; off >>= 1) {
        s_iou += __shfl_down(s_iou, off, 64);
        s_cnt += __shfl_down(s_cnt, off, 64);
    }

    __shared__ float lds_iou[THREADS / 64];
    __shared__ float lds_cnt[THREADS / 64];
    int lane = threadIdx.x & 63;
    int wave = threadIdx.x >> 6;
    if (lane == 0) {
        lds_iou[wave] = s_iou;
        lds_cnt[wave] = s_cnt;
    }
    __syncthreads();

    if (threadIdx.x == 0) {
        float a = 0.0f, b = 0.0f;
        #pragma unroll
        for (int w = 0; w < THREADS / 64; ++w) {
            a += lds_iou[w];
            b += lds_cnt[w];
        }
        partials[2 * blockIdx.x]     = a;
        partials[2 * blockIdx.x + 1] = b;
    }
}

__global__ __launch_bounds__(THREADS) void iou_finalize(
    const float* __restrict__ partials, int nblocks, float* __restrict__ out)
{
    float s_iou = 0.0f;
    float s_cnt = 0.0f;
    for (int i = threadIdx.x; i < nblocks; i += blockDim.x) {
        s_iou += partials[2 * i];
        s_cnt += partials[2 * i + 1];
    }
    for (int off = 32; off > 0; off >>= 1) {
        s_iou += __shfl_down(s_iou, off, 64);
        s_cnt += __shfl_down(s_cnt, off, 64);
    }
    __shared__ float lds_iou[THREADS / 64];
    __shared__ float lds_cnt[THREADS / 64];
    int lane = threadIdx.x & 63;
    int wave = threadIdx.x >> 6;
    if (lane == 0) {
        lds_iou[wave] = s_iou;
        lds_cnt[wave] = s_cnt;
    }
    __syncthreads();
    if (threadIdx.x == 0) {
        float a = 0.0f, b = 0.0f;
        #pragma unroll
        for (int w = 0; w < THREADS / 64; ++w) {
            a += lds_iou[w];
            b += lds_cnt[w];
        }
        out[0] = (b > 0.0f) ? (a / fmaxf(b, 1.0f)) : 0.0f;
    }
}

extern "C" void kernel_launch(void* const* d_in, const int* in_sizes, int n_in,
                              void* d_out, int out_size, void* d_ws, size_t ws_size,
                              hipStream_t stream) {
    const float4* pred  = (const float4*)d_in[0];
    const float4* truth = (const float4*)d_in[1];
    float* out = (float*)d_out;
    float* partials = (float*)d_ws;   // BLOCKS*2 floats, overwritten every call

    int n_pairs = in_sizes[0] / 4;    // B * NBOX

    iou_partial<<<BLOCKS, THREADS, 0, stream>>>(pred, truth, partials, n_pairs);
    iou_finalize<<<1, THREADS, 0, stream>>>(partials, BLOCKS, out);
}